// Round 1
// baseline (685.050 us; speedup 1.0000x reference)
//
#include <hip/hip_runtime.h>
#include <cstdint>
#include <cstddef>

typedef short short8 __attribute__((ext_vector_type(8)));
typedef float float4_ __attribute__((ext_vector_type(4)));
typedef unsigned int uint4_ __attribute__((ext_vector_type(4)));

#define DEVI static __device__ __forceinline__

DEVI unsigned short f2bf(float f) {
  union { float f; unsigned u; } v; v.f = f;
  return (unsigned short)((v.u + 0x7FFFu + ((v.u >> 16) & 1u)) >> 16);
}
DEVI float bf2f(unsigned short h) {
  union { unsigned u; float f; } v; v.u = ((unsigned)h) << 16;
  return v.f;
}

#define SCALE_Q 0.17677669529663687f  // 32^-0.5

// ---------------- K0: weight prep ----------------
// qkvWT[576][192] (bf16, q-cols pre-scaled), projWT[192][192], w1T[768][192],
// w2T[192][768], qkv_b_s[576] (f32, scaled), bias_attn[6][64][64] (f32)
__global__ __launch_bounds__(256) void k_prep(
    const float* __restrict__ qkv_w, const float* __restrict__ qkv_b,
    const float* __restrict__ proj_w, const float* __restrict__ mlp_w1,
    const float* __restrict__ mlp_w2, const float* __restrict__ relt,
    unsigned short* __restrict__ qkvWT, unsigned short* __restrict__ projWT,
    unsigned short* __restrict__ w1T, unsigned short* __restrict__ w2T,
    float* __restrict__ qkv_b_s, float* __restrict__ bias_attn) {
  int i = blockIdx.x * 256 + threadIdx.x;
  if (i < 110592) { int n = i / 192, k = i - n * 192;
    float v = qkv_w[k * 576 + n]; if (n < 192) v *= SCALE_Q;
    qkvWT[i] = f2bf(v); return; }
  i -= 110592;
  if (i < 576) { qkv_b_s[i] = qkv_b[i] * (i < 192 ? SCALE_Q : 1.0f); return; }
  i -= 576;
  if (i < 36864) { int n = i / 192, k = i - n * 192;
    projWT[i] = f2bf(proj_w[k * 192 + n]); return; }
  i -= 36864;
  if (i < 147456) { int n = i / 192, k = i - n * 192;
    w1T[i] = f2bf(mlp_w1[k * 768 + n]); return; }
  i -= 147456;
  if (i < 147456) { int n = i / 768, k = i - n * 768;
    w2T[i] = f2bf(mlp_w2[k * 192 + n]); return; }
  i -= 147456;
  if (i < 24576) {
    int h = i >> 12, nm = i & 4095, n = nm >> 6, m = nm & 63;
    int dr = (n >> 3) - (m >> 3) + 7, dc = (n & 7) - (m & 7) + 7;
    bias_attn[i] = relt[(dr * 15 + dc) * 6 + h];
  }
}

// ---------------- K1: dwconv3x3(+res) + shift + window partition + LN1 ----------------
// block = one window (64 tokens); thread t: pos = t>>2, q = t&3 handles 48 channels.
__global__ __launch_bounds__(256) void k_conv_ln(
    const float* __restrict__ x, const float* __restrict__ convw,
    const float* __restrict__ g1, const float* __restrict__ b1,
    unsigned short* __restrict__ xw, unsigned short* __restrict__ a) {
  __shared__ float s_w[1728];
  __shared__ float s_g[192], s_b[192];
  int t = threadIdx.x;
  for (int i = t; i < 1728; i += 256) s_w[i] = convw[i];
  for (int i = t; i < 192; i += 256) { s_g[i] = g1[i]; s_b[i] = b1[i]; }
  __syncthreads();
  int win = blockIdx.x;
  int b = win >> 8, wi = (win >> 4) & 15, wj = win & 15;
  int pos = t >> 2, q = t & 3;
  int h = (wi * 8 + (pos >> 3) + 4) & 127;   // source coords (shift roll -4,-4)
  int w = (wj * 8 + (pos & 7) + 4) & 127;
  const float* xb = x + ((size_t)b * 192) * 16384 + h * 128 + w;
  float mrow[3] = { h >= 1 ? 1.f : 0.f, 1.f, h <= 126 ? 1.f : 0.f };
  float mcol[3] = { w >= 1 ? 1.f : 0.f, 1.f, w <= 126 ? 1.f : 0.f };
  int orow[3] = { h >= 1 ? -128 : 0, 0, h <= 126 ? 128 : 0 };
  int ocol[3] = { w >= 1 ? -1 : 0, 0, w <= 126 ? 1 : 0 };
  float msk[9]; int off[9];
  #pragma unroll
  for (int dy = 0; dy < 3; ++dy)
    #pragma unroll
    for (int dx = 0; dx < 3; ++dx) {
      msk[dy * 3 + dx] = mrow[dy] * mcol[dx];
      off[dy * 3 + dx] = orow[dy] + ocol[dx];
    }
  int c0 = q * 48;
  float vals[48];
  float sum = 0.f, sq = 0.f;
  #pragma unroll
  for (int i = 0; i < 48; ++i) {
    int c = c0 + i;
    const float* xc = xb + (size_t)c * 16384;
    const float* wc = s_w + c * 9;
    float acc = xc[0];                  // residual
    #pragma unroll
    for (int tp = 0; tp < 9; ++tp) {
      float xv = xc[off[tp]] * msk[tp]; // zero-padded SAME conv
      acc = fmaf(wc[tp], xv, acc);
    }
    vals[i] = acc;
    sum += acc; sq = fmaf(acc, acc, sq);
  }
  sum += __shfl_xor(sum, 1); sum += __shfl_xor(sum, 2);
  sq  += __shfl_xor(sq, 1);  sq  += __shfl_xor(sq, 2);
  float mu = sum * (1.f / 192.f);
  float var = sq * (1.f / 192.f) - mu * mu;
  float rs = rsqrtf(var + 1e-5f);
  size_t tok = (size_t)win * 64 + pos;
  unsigned short* xwp = xw + tok * 192 + c0;
  unsigned short* ap  = a  + tok * 192 + c0;
  #pragma unroll
  for (int i0 = 0; i0 < 48; i0 += 8) {
    unsigned px[4], pa[4];
    #pragma unroll
    for (int j = 0; j < 4; ++j) {
      float v0 = vals[i0 + 2 * j], v1 = vals[i0 + 2 * j + 1];
      int c = c0 + i0 + 2 * j;
      px[j] = (unsigned)f2bf(v0) | ((unsigned)f2bf(v1) << 16);
      float a0 = (v0 - mu) * rs * s_g[c] + s_b[c];
      float a1 = (v1 - mu) * rs * s_g[c + 1] + s_b[c + 1];
      pa[j] = (unsigned)f2bf(a0) | ((unsigned)f2bf(a1) << 16);
    }
    uint4_ vx = { px[0], px[1], px[2], px[3] };
    uint4_ va = { pa[0], pa[1], pa[2], pa[3] };
    *(uint4_*)(xwp + i0) = vx;
    *(uint4_*)(ap + i0)  = va;
  }
}

// ---------------- K2: QKV GEMM  (M=131072, N=576, K=192) ----------------
// BM=128 BN=64, full K resident in LDS, XOR-swizzled tiles, 4 waves (2x2), wave tile 64x32.
__global__ __launch_bounds__(256) void k_qkv(
    const unsigned short* __restrict__ a, const unsigned short* __restrict__ wT,
    const float* __restrict__ bias, unsigned short* __restrict__ outq) {
  __shared__ __align__(16) unsigned short sA[128 * 192];
  __shared__ __align__(16) unsigned short sB[64 * 192];
  int bid = blockIdx.x;
  int nblk = bid % 9, mblk = bid / 9;
  int t = threadIdx.x;
  const unsigned short* aBase = a + (size_t)mblk * (128 * 192);
  #pragma unroll
  for (int i = 0; i < 12; ++i) {             // 3072 16B-chunks
    int chunk = t + i * 256;
    int row = (chunk * 2731) >> 16;          // chunk/24
    uint4_ v = *(const uint4_*)(aBase + chunk * 8);
    *(uint4_*)((char*)sA + ((chunk * 16) ^ ((row & 7) << 4))) = v;
  }
  const unsigned short* bBase = wT + (size_t)nblk * (64 * 192);
  #pragma unroll
  for (int i = 0; i < 6; ++i) {              // 1536 chunks
    int chunk = t + i * 256;
    int row = (chunk * 2731) >> 16;
    uint4_ v = *(const uint4_*)(bBase + chunk * 8);
    *(uint4_*)((char*)sB + ((chunk * 16) ^ ((row & 7) << 4))) = v;
  }
  __syncthreads();
  int lane = t & 63, wv = t >> 6;
  int wm = wv >> 1, wn = wv & 1;
  int lrow = lane & 15, lkgrp = lane >> 4, lk = lkgrp * 8;
  float4_ acc[4][2];
  #pragma unroll
  for (int mi = 0; mi < 4; ++mi)
    #pragma unroll
    for (int ni = 0; ni < 2; ++ni) acc[mi][ni] = (float4_){0.f, 0.f, 0.f, 0.f};
  #pragma unroll
  for (int ks = 0; ks < 6; ++ks) {
    int kb = ks * 32 + lk;
    short8 af[4], bf[2];
    #pragma unroll
    for (int mi = 0; mi < 4; ++mi) {
      int row = wm * 64 + mi * 16 + lrow;
      af[mi] = *(const short8*)((const char*)sA + ((row * 384 + kb * 2) ^ ((row & 7) << 4)));
    }
    #pragma unroll
    for (int ni = 0; ni < 2; ++ni) {
      int col = wn * 32 + ni * 16 + lrow;
      bf[ni] = *(const short8*)((const char*)sB + ((col * 384 + kb * 2) ^ ((col & 7) << 4)));
    }
    #pragma unroll
    for (int mi = 0; mi < 4; ++mi)
      #pragma unroll
      for (int ni = 0; ni < 2; ++ni)
        acc[mi][ni] = __builtin_amdgcn_mfma_f32_16x16x32_bf16(af[mi], bf[ni], acc[mi][ni], 0, 0, 0);
  }
  int grow0 = mblk * 128 + wm * 64;
  #pragma unroll
  for (int ni = 0; ni < 2; ++ni) {
    int col = nblk * 64 + wn * 32 + ni * 16 + lrow;
    float bv = bias[col];
    #pragma unroll
    for (int mi = 0; mi < 4; ++mi) {
      #pragma unroll
      for (int e = 0; e < 4; ++e) {
        int row = grow0 + mi * 16 + lkgrp * 4 + e;
        outq[(size_t)row * 576 + col] = f2bf(acc[mi][ni][e] + bv);
      }
    }
  }
}

// ---------------- K3: windowed attention (one wave per head) ----------------
__global__ __launch_bounds__(384) void k_attn(
    const unsigned short* __restrict__ qkv, const float* __restrict__ biasAll,
    unsigned short* __restrict__ outO) {
  __shared__ __align__(16) unsigned short sVT[6][2048];  // V^T [32][64] per head
  __shared__ __align__(16) unsigned short sP[6][4096];   // P   [64][64] per head
  int t = threadIdx.x, lane = t & 63, head = t >> 6;
  int win = blockIdx.x;
  int wi = (win >> 4) & 15, wj = win & 15;
  const unsigned short* base = qkv + (size_t)win * (64 * 576);
  int lrow = lane & 15, lkgrp = lane >> 4, lk = lkgrp * 8;
  // Q/K fragments straight from global (L2/L3-hot)
  short8 qf[4], kf[4];
  #pragma unroll
  for (int mi = 0; mi < 4; ++mi) {
    const unsigned short* rp = base + (size_t)(mi * 16 + lrow) * 576 + head * 32 + lk;
    qf[mi] = *(const short8*)(rp);
    kf[mi] = *(const short8*)(rp + 192);
  }
  // V transpose into LDS (swizzled)
  {
    const unsigned short* vrow = base + (size_t)lane * 576 + 384 + head * 32;
    short8 vv[4];
    #pragma unroll
    for (int j = 0; j < 4; ++j) vv[j] = *(const short8*)(vrow + j * 8);
    char* vt = (char*)sVT[head];
    #pragma unroll
    for (int j = 0; j < 4; ++j)
      #pragma unroll
      for (int e = 0; e < 8; ++e) {
        int d = j * 8 + e;
        *(unsigned short*)(vt + ((d * 128 + lane * 2) ^ ((d & 7) << 4))) = (unsigned short)vv[j][e];
      }
  }
  // S = (q*scale) @ k^T     (scale pre-folded into q)
  float4_ s[4][4];
  #pragma unroll
  for (int mi = 0; mi < 4; ++mi)
    #pragma unroll
    for (int ni = 0; ni < 4; ++ni) {
      s[mi][ni] = (float4_){0.f, 0.f, 0.f, 0.f};
      s[mi][ni] = __builtin_amdgcn_mfma_f32_16x16x32_bf16(qf[mi], kf[ni], s[mi][ni], 0, 0, 0);
    }
  const float* bh = biasAll + head * 4096;
  bool wi15 = (wi == 15), wj15 = (wj == 15);
  bool edge = wi15 || wj15;
  char* sp = (char*)sP[head];
  #pragma unroll
  for (int mi = 0; mi < 4; ++mi) {
    #pragma unroll
    for (int e = 0; e < 4; ++e) {
      int row = mi * 16 + lkgrp * 4 + e;           // query pos
      int rcls = (wi15 ? ((row >> 3) >= 4 ? 2 : 1) : 0) * 3 +
                 (wj15 ? ((row & 7) >= 4 ? 2 : 1) : 0);
      float v[4];
      #pragma unroll
      for (int ni = 0; ni < 4; ++ni) {
        int col = ni * 16 + lrow;                  // key pos
        float xv = s[mi][ni][e] + bh[row * 64 + col];
        if (edge) {
          int ccls = (wi15 ? ((col >> 3) >= 4 ? 2 : 1) : 0) * 3 +
                     (wj15 ? ((col & 7) >= 4 ? 2 : 1) : 0);
          if (ccls != rcls) xv -= 100.f;
        }
        v[ni] = xv;
      }
      float mx = fmaxf(fmaxf(v[0], v[1]), fmaxf(v[2], v[3]));
      mx = fmaxf(mx, __shfl_xor(mx, 1));
      mx = fmaxf(mx, __shfl_xor(mx, 2));
      mx = fmaxf(mx, __shfl_xor(mx, 4));
      mx = fmaxf(mx, __shfl_xor(mx, 8));
      float sm = 0.f;
      #pragma unroll
      for (int ni = 0; ni < 4; ++ni) { v[ni] = __expf(v[ni] - mx); sm += v[ni]; }
      sm += __shfl_xor(sm, 1);
      sm += __shfl_xor(sm, 2);
      sm += __shfl_xor(sm, 4);
      sm += __shfl_xor(sm, 8);
      float inv = 1.f / sm;
      #pragma unroll
      for (int ni = 0; ni < 4; ++ni) {
        int col = ni * 16 + lrow;
        *(unsigned short*)(sp + ((row * 128 + col * 2) ^ ((row & 7) << 4))) = f2bf(v[ni] * inv);
      }
    }
  }
  __syncthreads();
  // O = P @ V
  float4_ o[4][2];
  #pragma unroll
  for (int mi = 0; mi < 4; ++mi)
    #pragma unroll
    for (int ni = 0; ni < 2; ++ni) o[mi][ni] = (float4_){0.f, 0.f, 0.f, 0.f};
  char* vt = (char*)sVT[head];
  #pragma unroll
  for (int kk = 0; kk < 2; ++kk) {
    int ktok = kk * 32 + lk;
    short8 pf[4], vf[2];
    #pragma unroll
    for (int mi = 0; mi < 4; ++mi) {
      int row = mi * 16 + lrow;
      pf[mi] = *(const short8*)(sp + ((row * 128 + ktok * 2) ^ ((row & 7) << 4)));
    }
    #pragma unroll
    for (int ni = 0; ni < 2; ++ni) {
      int d = ni * 16 + lrow;
      vf[ni] = *(const short8*)(vt + ((d * 128 + ktok * 2) ^ ((d & 7) << 4)));
    }
    #pragma unroll
    for (int mi = 0; mi < 4; ++mi)
      #pragma unroll
      for (int ni = 0; ni < 2; ++ni)
        o[mi][ni] = __builtin_amdgcn_mfma_f32_16x16x32_bf16(pf[mi], vf[ni], o[mi][ni], 0, 0, 0);
  }
  unsigned short* ob = outO + (size_t)win * (64 * 192) + head * 32;
  #pragma unroll
  for (int mi = 0; mi < 4; ++mi)
    #pragma unroll
    for (int ni = 0; ni < 2; ++ni)
      #pragma unroll
      for (int e = 0; e < 4; ++e) {
        int row = mi * 16 + lkgrp * 4 + e;
        int col = ni * 16 + lrow;
        ob[(size_t)row * 192 + col] = f2bf(o[mi][ni][e]);
      }
}

// ---------------- K4: proj + residual + LN2 + MLP(GELU) + residual + un-window ----------------
// block = 128 tokens (2 horizontally adjacent windows), 512 threads = 8 waves (2m x 4n).
__global__ __launch_bounds__(512) void k_mlp(
    const unsigned short* __restrict__ O, const unsigned short* __restrict__ xw,
    const unsigned short* __restrict__ projWT, const float* __restrict__ proj_b,
    const float* __restrict__ n2g, const float* __restrict__ n2b,
    const unsigned short* __restrict__ w1T, const float* __restrict__ mlpb1,
    const unsigned short* __restrict__ w2T, const float* __restrict__ mlpb2,
    float* __restrict__ y) {
  __shared__ __align__(16) char smem[3 * 49152 + 1536];
  unsigned short* sO   = (unsigned short*)smem;               // later: ytile float[128][96]
  unsigned short* sH   = (unsigned short*)(smem + 49152);
  unsigned short* sBuf = (unsigned short*)(smem + 2 * 49152); // hid chunk; aliases sRed
  float* sRed = (float*)(smem + 2 * 49152);                   // [128][4][2]
  float* sG = (float*)(smem + 3 * 49152);
  float* sBn = sG + 192;
  int t = threadIdx.x, lane = t & 63, wv = t >> 6;
  int wm = wv >> 2, wn = wv & 3;
  int lrow = lane & 15, lkgrp = lane >> 4, lk = lkgrp * 8;
  int blk = blockIdx.x;
  for (int i = t; i < 192; i += 512) { sG[i] = n2g[i]; sBn[i] = n2b[i]; }
  const unsigned short* obase = O + (size_t)blk * (128 * 192);
  #pragma unroll
  for (int i = 0; i < 6; ++i) {
    int chunk = t + i * 512;
    int row = (chunk * 2731) >> 16;
    uint4_ v = *(const uint4_*)(obase + chunk * 8);
    *(uint4_*)((char*)sO + ((chunk * 16) ^ ((row & 7) << 4))) = v;
  }
  __syncthreads();
  // ---- proj ----
  float4_ tacc[4][3];
  #pragma unroll
  for (int mi = 0; mi < 4; ++mi)
    #pragma unroll
    for (int ni = 0; ni < 3; ++ni) tacc[mi][ni] = (float4_){0.f, 0.f, 0.f, 0.f};
  #pragma unroll
  for (int ks = 0; ks < 6; ++ks) {
    int kb = ks * 32 + lk;
    short8 af[4], bf[3];
    #pragma unroll
    for (int mi = 0; mi < 4; ++mi) {
      int row = wm * 64 + mi * 16 + lrow;
      af[mi] = *(const short8*)((const char*)sO + ((row * 384 + kb * 2) ^ ((row & 7) << 4)));
    }
    #pragma unroll
    for (int ni = 0; ni < 3; ++ni) {
      int col = wn * 48 + ni * 16 + lrow;
      bf[ni] = *(const short8*)(projWT + (size_t)col * 192 + kb);
    }
    #pragma unroll
    for (int mi = 0; mi < 4; ++mi)
      #pragma unroll
      for (int ni = 0; ni < 3; ++ni)
        tacc[mi][ni] = __builtin_amdgcn_mfma_f32_16x16x32_bf16(af[mi], bf[ni], tacc[mi][ni], 0, 0, 0);
  }
  // t = proj + proj_b + xw   (windows2, stays in registers)
  #pragma unroll
  for (int ni = 0; ni < 3; ++ni) {
    int col = wn * 48 + ni * 16 + lrow;
    float pbv = proj_b[col];
    #pragma unroll
    for (int mi = 0; mi < 4; ++mi)
      #pragma unroll
      for (int e = 0; e < 4; ++e) {
        int row = wm * 64 + mi * 16 + lkgrp * 4 + e;
        float xv = bf2f(xw[(size_t)(blk * 128 + row) * 192 + col]);
        tacc[mi][ni][e] += pbv + xv;
      }
  }
  // ---- LN2 ----
  #pragma unroll
  for (int mi = 0; mi < 4; ++mi)
    #pragma unroll
    for (int e = 0; e < 4; ++e) {
      float s1 = tacc[mi][0][e] + tacc[mi][1][e] + tacc[mi][2][e];
      float s2 = tacc[mi][0][e] * tacc[mi][0][e] + tacc[mi][1][e] * tacc[mi][1][e] +
                 tacc[mi][2][e] * tacc[mi][2][e];
      s1 += __shfl_xor(s1, 1); s1 += __shfl_xor(s1, 2); s1 += __shfl_xor(s1, 4); s1 += __shfl_xor(s1, 8);
      s2 += __shfl_xor(s2, 1); s2 += __shfl_xor(s2, 2); s2 += __shfl_xor(s2, 4); s2 += __shfl_xor(s2, 8);
      if (lrow == 0) {
        int row = wm * 64 + mi * 16 + lkgrp * 4 + e;
        sRed[row * 8 + wn * 2 + 0] = s1;
        sRed[row * 8 + wn * 2 + 1] = s2;
      }
    }
  __syncthreads();
  #pragma unroll
  for (int mi = 0; mi < 4; ++mi)
    #pragma unroll
    for (int e = 0; e < 4; ++e) {
      int row = wm * 64 + mi * 16 + lkgrp * 4 + e;
      float s1 = sRed[row * 8] + sRed[row * 8 + 2] + sRed[row * 8 + 4] + sRed[row * 8 + 6];
      float s2 = sRed[row * 8 + 1] + sRed[row * 8 + 3] + sRed[row * 8 + 5] + sRed[row * 8 + 7];
      float mu = s1 * (1.f / 192.f);
      float var = s2 * (1.f / 192.f) - mu * mu;
      float rs = rsqrtf(var + 1e-5f);
      #pragma unroll
      for (int ni = 0; ni < 3; ++ni) {
        int col = wn * 48 + ni * 16 + lrow;
        float hv = (tacc[mi][ni][e] - mu) * rs * sG[col] + sBn[col];
        *(unsigned short*)((char*)sH + ((row * 384 + col * 2) ^ ((row & 7) << 4))) = f2bf(hv);
      }
    }
  __syncthreads();
  // ---- MLP: 4 chunks of 192; hid never leaves LDS; o2 starts from t (residual) ----
  float4_ o2[4][3];
  #pragma unroll
  for (int mi = 0; mi < 4; ++mi)
    #pragma unroll
    for (int ni = 0; ni < 3; ++ni) o2[mi][ni] = tacc[mi][ni];
  for (int ch = 0; ch < 4; ++ch) {
    float4_ h1[4][3];
    #pragma unroll
    for (int mi = 0; mi < 4; ++mi)
      #pragma unroll
      for (int ni = 0; ni < 3; ++ni) h1[mi][ni] = (float4_){0.f, 0.f, 0.f, 0.f};
    #pragma unroll
    for (int ks = 0; ks < 6; ++ks) {
      int kb = ks * 32 + lk;
      short8 af[4], bf[3];
      #pragma unroll
      for (int mi = 0; mi < 4; ++mi) {
        int row = wm * 64 + mi * 16 + lrow;
        af[mi] = *(const short8*)((const char*)sH + ((row * 384 + kb * 2) ^ ((row & 7) << 4)));
      }
      #pragma unroll
      for (int ni = 0; ni < 3; ++ni) {
        int gn = ch * 192 + wn * 48 + ni * 16 + lrow;
        bf[ni] = *(const short8*)(w1T + (size_t)gn * 192 + kb);
      }
      #pragma unroll
      for (int mi = 0; mi < 4; ++mi)
        #pragma unroll
        for (int ni = 0; ni < 3; ++ni)
          h1[mi][ni] = __builtin_amdgcn_mfma_f32_16x16x32_bf16(af[mi], bf[ni], h1[mi][ni], 0, 0, 0);
    }
    // exact GELU -> sBuf
    #pragma unroll
    for (int ni = 0; ni < 3; ++ni) {
      int gn = ch * 192 + wn * 48 + ni * 16 + lrow;
      float b1v = mlpb1[gn];
      #pragma unroll
      for (int mi = 0; mi < 4; ++mi)
        #pragma unroll
        for (int e = 0; e < 4; ++e) {
          float v = h1[mi][ni][e] + b1v;
          v = 0.5f * v * (1.f + erff(v * 0.70710678118f));
          int row = wm * 64 + mi * 16 + lkgrp * 4 + e;
          int col = wn * 48 + ni * 16 + lrow;
          *(unsigned short*)((char*)sBuf + ((row * 384 + col * 2) ^ ((row & 7) << 4))) = f2bf(v);
        }
    }
    __syncthreads();
    // o2 += hid_chunk @ w2T[:, ch-slice]
    #pragma unroll
    for (int ks = 0; ks < 6; ++ks) {
      int kb = ks * 32 + lk;
      short8 af[4], bf[3];
      #pragma unroll
      for (int mi = 0; mi < 4; ++mi) {
        int row = wm * 64 + mi * 16 + lrow;
        af[mi] = *(const short8*)((const char*)sBuf + ((row * 384 + kb * 2) ^ ((row & 7) << 4)));
      }
      #pragma unroll
      for (int ni = 0; ni < 3; ++ni) {
        int col = wn * 48 + ni * 16 + lrow;
        bf[ni] = *(const short8*)(w2T + (size_t)col * 768 + ch * 192 + kb);
      }
      #pragma unroll
      for (int mi = 0; mi < 4; ++mi)
        #pragma unroll
        for (int ni = 0; ni < 3; ++ni)
          o2[mi][ni] = __builtin_amdgcn_mfma_f32_16x16x32_bf16(af[mi], bf[ni], o2[mi][ni], 0, 0, 0);
    }
    __syncthreads();
  }
  // ---- epilogue: + mlp_b2, un-window + roll(+4,+4), via LDS transpose, 2 column halves ----
  int b = blk >> 7, wi = (blk >> 3) & 15, wj0 = (blk & 7) * 2;
  float* yt = (float*)smem;
  for (int hf = 0; hf < 2; ++hf) {
    __syncthreads();
    if ((wn >> 1) == hf) {
      int cb = (wn & 1) * 48;
      #pragma unroll
      for (int ni = 0; ni < 3; ++ni) {
        int col = wn * 48 + ni * 16 + lrow;
        float b2v = mlpb2[col];
        int colh = cb + ni * 16 + lrow;
        #pragma unroll
        for (int mi = 0; mi < 4; ++mi)
          #pragma unroll
          for (int e = 0; e < 4; ++e) {
            int row = wm * 64 + mi * 16 + lkgrp * 4 + e;
            yt[(row * 96 + colh) ^ (row & 31)] = o2[mi][ni][e] + b2v;
          }
      }
    }
    __syncthreads();
    #pragma unroll
    for (int it = 0; it < 6; ++it) {
      int id = t + it * 512;                 // 0..3071 : (chh, r, s)
      int chh = id >> 5, r = (id >> 2) & 7, s = id & 3;
      int ch = hf * 96 + chh;
      int h = (wi * 8 + r + 4) & 127;
      float v[4];
      #pragma unroll
      for (int j = 0; j < 4; ++j) {
        int p = s * 4 + j;                   // pos in 16-wide strip
        int tok = (p >> 3) * 64 + r * 8 + (p & 7);
        v[j] = yt[(tok * 96 + chh) ^ (tok & 31)];
      }
      int w = (wj0 * 8 + 4 + s * 4) & 127;
      float4_ vv = { v[0], v[1], v[2], v[3] };
      *(float4_*)(y + (((size_t)(b * 192 + ch) * 128 + h) * 128 + w)) = vv;
    }
  }
}

extern "C" void kernel_launch(void* const* d_in, const int* in_sizes, int n_in,
                              void* d_out, int out_size, void* d_ws, size_t ws_size,
                              hipStream_t stream) {
  (void)in_sizes; (void)n_in; (void)out_size;
  const float* x    = (const float*)d_in[0];
  const float* pcw  = (const float*)d_in[1];
  const float* n1g  = (const float*)d_in[2];
  const float* n1b  = (const float*)d_in[3];
  const float* qkvw = (const float*)d_in[4];
  const float* qkvb = (const float*)d_in[5];
  const float* pw   = (const float*)d_in[6];
  const float* pb   = (const float*)d_in[7];
  const float* relt = (const float*)d_in[8];
  const float* n2g  = (const float*)d_in[9];
  const float* n2b  = (const float*)d_in[10];
  const float* w1   = (const float*)d_in[11];
  const float* mb1  = (const float*)d_in[12];
  const float* w2   = (const float*)d_in[13];
  const float* mb2  = (const float*)d_in[14];
  float* y = (float*)d_out;
  char* ws = (char*)d_ws;
  size_t off = 0;
  auto carve = [&](size_t bytes) { void* p = ws + off; off += (bytes + 255) & ~(size_t)255; return p; };
  unsigned short* qkvWT  = (unsigned short*)carve(576 * 192 * 2);
  unsigned short* projWT = (unsigned short*)carve(192 * 192 * 2);
  unsigned short* w1T    = (unsigned short*)carve(768 * 192 * 2);
  unsigned short* w2T    = (unsigned short*)carve(192 * 768 * 2);
  float* qkv_b_s   = (float*)carve(576 * 4);
  float* bias_attn = (float*)carve(6 * 64 * 64 * 4);
  unsigned short* aBuf   = (unsigned short*)carve((size_t)131072 * 192 * 2); // LN1 out, then attn O
  unsigned short* xwBuf  = (unsigned short*)carve((size_t)131072 * 192 * 2); // residual stream
  unsigned short* qkvBuf = (unsigned short*)carve((size_t)131072 * 576 * 2);
  if (off > ws_size) return;  // workspace too small: fail visibly

  k_prep<<<dim3(1827), dim3(256), 0, stream>>>(qkvw, qkvb, pw, w1, w2, relt,
                                               qkvWT, projWT, w1T, w2T, qkv_b_s, bias_attn);
  k_conv_ln<<<dim3(2048), dim3(256), 0, stream>>>(x, pcw, n1g, n1b, xwBuf, aBuf);
  k_qkv<<<dim3(9216), dim3(256), 0, stream>>>(aBuf, qkvWT, qkv_b_s, qkvBuf);
  k_attn<<<dim3(2048), dim3(384), 0, stream>>>(qkvBuf, bias_attn, aBuf);
  k_mlp<<<dim3(1024), dim3(512), 0, stream>>>(aBuf, xwBuf, projWT, pb, n2g, n2b,
                                              w1T, mb1, w2T, mb2, y);
}